// Round 9
// baseline (165.748 us; speedup 1.0000x reference)
//
#include <hip/hip_runtime.h>
#include <hip/hip_bf16.h>
#include <math.h>

#define B_   64
#define C_   768
#define C2_  1536
#define R_   96
#define E_   16
#define HW_  1024

typedef float f32x4 __attribute__((ext_vector_type(4)));

__device__ __forceinline__ float gelu_exact(float x) {
    return 0.5f * x * (1.0f + erff(x * 0.70710678118654752440f));
}

// -------- Kernel 1: global average pool [B,C,H,W] -> gT[C][B] ---------------
// one wave per row; block 0 also zeroes r_pre (visible at kernel boundary).
__global__ __launch_bounds__(256) void pool_kernel(const float* __restrict__ x,
                                                   float* __restrict__ gT,
                                                   float* __restrict__ r_pre) {
    if (blockIdx.x == 0) {
        #pragma unroll
        for (int i = 0; i < (R_ * B_) / 256; ++i)
            r_pre[i * 256 + threadIdx.x] = 0.0f;
    }
    const int wave = threadIdx.x >> 6;
    const int lane = threadIdx.x & 63;
    const int row  = blockIdx.x * 4 + wave;
    const int b = row / C_;
    const int c = row % C_;
    const f32x4* p = reinterpret_cast<const f32x4*>(x + (size_t)row * HW_);
    f32x4 a0 = __builtin_nontemporal_load(p + lane +   0);
    f32x4 a1 = __builtin_nontemporal_load(p + lane +  64);
    f32x4 a2 = __builtin_nontemporal_load(p + lane + 128);
    f32x4 a3 = __builtin_nontemporal_load(p + lane + 192);
    float s = (a0.x + a0.y + a0.z + a0.w) + (a1.x + a1.y + a1.z + a1.w)
            + (a2.x + a2.y + a2.z + a2.w) + (a3.x + a3.y + a3.z + a3.w);
    #pragma unroll
    for (int off = 32; off >= 1; off >>= 1) s += __shfl_xor(s, off);
    if (lane == 0) gT[c * B_ + b] = s * (1.0f / (float)HW_);
}

// -------- L1 + split-K r: h1T = gelu(bn1(g @ w1.T + b1)); 6 c per block; ----
// then atomically accumulate this block's contribution to r_pre = h1 @ caw1.T
__global__ __launch_bounds__(512) void l1r_kernel(
    const float* __restrict__ gT,
    const float* __restrict__ w1, const float* __restrict__ b1,
    const float* __restrict__ bn_g, const float* __restrict__ bn_b,
    const float* __restrict__ bn_m, const float* __restrict__ bn_v,
    const float* __restrict__ caw1,
    float* __restrict__ h1T, float* __restrict__ r_pre)
{
    __shared__ __align__(16) float wl[6 * C_];      // 18 KB
    __shared__ float part[6][8][64];                // 12 KB
    __shared__ float hl[6][64];                     // 1.5 KB
    const int t  = threadIdx.x;
    const int c0 = blockIdx.x * 6;
    {
        const float4* src = reinterpret_cast<const float4*>(w1 + (size_t)c0 * C_);
        float4* dst = reinterpret_cast<float4*>(wl);
        #pragma unroll
        for (int i = 0; i < 3; ++i) {
            int idx = t + i * 512;
            if (idx < 1152) dst[idx] = src[idx];
        }
    }
    __syncthreads();
    const int b = t & 63, w = t >> 6;
    const int kc = w * 96;
    float acc[6] = {0.f, 0.f, 0.f, 0.f, 0.f, 0.f};
    const float* gp = gT + (size_t)kc * B_ + b;
    #pragma unroll 8
    for (int k = 0; k < 96; ++k) {
        float gv = gp[k * B_];
        #pragma unroll
        for (int j = 0; j < 6; ++j)
            acc[j] = fmaf(gv, wl[j * C_ + kc + k], acc[j]);
    }
    #pragma unroll
    for (int j = 0; j < 6; ++j) part[j][w][b] = acc[j];
    __syncthreads();
    if (t < 384) {
        const int ci = t >> 6, bb = t & 63, c = c0 + ci;
        float s = 0.f;
        #pragma unroll
        for (int ww = 0; ww < 8; ++ww) s += part[ci][ww][bb];
        s += b1[c];
        s = (s - bn_m[c]) * rsqrtf(bn_v[c] + 1e-5f) * bn_g[c] + bn_b[c];
        float h = gelu_exact(s);
        h1T[(size_t)c * B_ + bb] = h;
        hl[ci][bb] = h;
    }
    __syncthreads();
    // r_pre[j][b] += sum_ci caw1[j][c0+ci] * hl[ci][b]; t<192: (j, half of b)
    if (t < 192) {
        const int j = t % 96, half = t / 96;          // half in {0,1}
        float cw[6];
        #pragma unroll
        for (int ci = 0; ci < 6; ++ci) cw[ci] = caw1[(size_t)j * C2_ + c0 + ci];
        float* rp = r_pre + j * B_ + half * 32;
        #pragma unroll 4
        for (int bb = 0; bb < 32; ++bb) {
            float v = 0.f;
            #pragma unroll
            for (int ci = 0; ci < 6; ++ci) v = fmaf(cw[ci], hl[ci][half * 32 + bb], v);
            atomicAdd(&rp[bb], v);
        }
    }
}

// -------- Gate: r = gelu(r_pre + cab1) (in LDS); h1gT = h1T * sigmoid(2a) ---
// 192 blocks x 8 waves, wave = one channel c
__global__ __launch_bounds__(512) void gate_kernel(
    const float* __restrict__ r_pre, const float* __restrict__ cab1,
    const float* __restrict__ caw2, const float* __restrict__ cab2,
    const float* __restrict__ h1T, float* __restrict__ h1gT)
{
    __shared__ __align__(16) float rl[R_ * B_];     // 24 KB, [j][b]
    const int t = threadIdx.x;
    {   // stage + gelu: 6144 floats = 1536 float4 (4 consecutive b, same j)
        const float4* src = reinterpret_cast<const float4*>(r_pre);
        float4* dst = reinterpret_cast<float4*>(rl);
        #pragma unroll
        for (int i = 0; i < 3; ++i) {
            int idx = t + i * 512;
            float4 v = src[idx];
            float cb = cab1[idx >> 4];   // j = (idx*4)/64
            v.x = gelu_exact(v.x + cb);
            v.y = gelu_exact(v.y + cb);
            v.z = gelu_exact(v.z + cb);
            v.w = gelu_exact(v.w + cb);
            dst[idx] = v;
        }
    }
    __syncthreads();
    const int b = t & 63, w = t >> 6;
    const int c = blockIdx.x * 8 + w;
    const int cu = __builtin_amdgcn_readfirstlane(c);
    const float* wr = caw2 + (size_t)cu * R_;       // wave-uniform -> s_loads
    float a0 = 0.f, a1 = 0.f;
    #pragma unroll 8
    for (int k = 0; k < 48; ++k) {
        a0 = fmaf(rl[k * B_ + b],        wr[k],      a0);
        a1 = fmaf(rl[(k + 48) * B_ + b], wr[k + 48], a1);
    }
    float a = a0 + a1 + cab2[cu];
    float sig = 1.0f / (1.0f + expf(-2.0f * a));
    h1gT[(size_t)cu * B_ + b] = h1T[(size_t)cu * B_ + b] * sig;
}

// -------- L4: h2T = gelu(bn2(h1g @ w2.T + b2)); 2 c per block, 384 blocks ---
__global__ __launch_bounds__(512) void l4_kernel(
    const float* __restrict__ h1gT, const float* __restrict__ w2,
    const float* __restrict__ b2,
    const float* __restrict__ bn_g, const float* __restrict__ bn_b,
    const float* __restrict__ bn_m, const float* __restrict__ bn_v,
    float* __restrict__ h2T)
{
    __shared__ __align__(16) float wl[2 * C2_];     // 12 KB
    __shared__ float part[2][8][64];                // 4 KB
    const int t  = threadIdx.x;
    const int c0 = blockIdx.x * 2;
    {
        const float4* src = reinterpret_cast<const float4*>(w2 + (size_t)c0 * C2_);
        float4* dst = reinterpret_cast<float4*>(wl);
        #pragma unroll
        for (int i = 0; i < 2; ++i) {
            int idx = t + i * 512;
            if (idx < 768) dst[idx] = src[idx];
        }
    }
    __syncthreads();
    const int b = t & 63, w = t >> 6;
    const int kc = w * 192;
    float a00 = 0.f, a01 = 0.f, a10 = 0.f, a11 = 0.f;
    const float* hp = h1gT + (size_t)kc * B_ + b;
    #pragma unroll 8
    for (int k = 0; k < 96; ++k) {
        float h0 = hp[k * B_];
        float h1 = hp[(k + 96) * B_];
        a00 = fmaf(h0, wl[kc + k],            a00);
        a01 = fmaf(h1, wl[kc + k + 96],       a01);
        a10 = fmaf(h0, wl[C2_ + kc + k],      a10);
        a11 = fmaf(h1, wl[C2_ + kc + k + 96], a11);
    }
    part[0][w][b] = a00 + a01;
    part[1][w][b] = a10 + a11;
    __syncthreads();
    if (t < 128) {
        const int ci = t >> 6, bb = t & 63, c = c0 + ci;
        float s = 0.f;
        #pragma unroll
        for (int ww = 0; ww < 8; ++ww) s += part[ci][ww][bb];
        s += b2[c];
        s = (s - bn_m[c]) * rsqrtf(bn_v[c] + 1e-5f) * bn_g[c] + bn_b[c];
        h2T[(size_t)c * B_ + bb] = gelu_exact(s);
    }
}

// -------- L5: scores + top-2 + softmax, one block per batch row ------------
__global__ __launch_bounds__(256) void l5_kernel(
    const float* __restrict__ h2T, const float* __restrict__ w3,
    const float* __restrict__ b3, float* __restrict__ out)
{
    __shared__ __align__(16) float wl[E_ * C_];   // 48 KB
    __shared__ float part[256];
    __shared__ float sc[E_];
    const int t = threadIdx.x;
    const int b = blockIdx.x;
    {
        const float4* src = reinterpret_cast<const float4*>(w3);
        float4* dst = reinterpret_cast<float4*>(wl);
        #pragma unroll
        for (int i = 0; i < 12; ++i) dst[t + 256 * i] = src[t + 256 * i];
    }
    __syncthreads();
    const int e = t & 15, kg = t >> 4;            // kg in [0,16)
    const float* wr = wl + e * C_ + kg * 48;
    const float* hv = h2T + (size_t)kg * 48 * B_ + b;
    float acc = 0.f;
    #pragma unroll 8
    for (int j = 0; j < 48; ++j) acc = fmaf(hv[j * B_], wr[j], acc);
    part[t] = acc;
    __syncthreads();
    if (t < E_) {
        float s = b3[t];
        #pragma unroll
        for (int kgi = 0; kgi < 16; ++kgi) s += part[kgi * 16 + t];
        sc[t] = s;
    }
    __syncthreads();
    if (t == 0) {
        int i0 = 0; float v0 = sc[0];
        #pragma unroll
        for (int i = 1; i < E_; ++i) { if (sc[i] > v0) { v0 = sc[i]; i0 = i; } }
        int i1 = -1; float v1 = -INFINITY;
        #pragma unroll
        for (int i = 0; i < E_; ++i) {
            if (i == i0) continue;
            if (sc[i] > v1) { v1 = sc[i]; i1 = i; }
        }
        float e1 = expf((v1 - v0) * 0.5f);
        float inv = 1.0f / (1.0f + e1);
        out[b * 2 + 0] = (float)i0;
        out[b * 2 + 1] = (float)i1;
        out[2 * B_ + b * 2 + 0] = inv;
        out[2 * B_ + b * 2 + 1] = e1 * inv;
    }
}

extern "C" void kernel_launch(void* const* d_in, const int* in_sizes, int n_in,
                              void* d_out, int out_size, void* d_ws, size_t ws_size,
                              hipStream_t stream) {
    const float* x     = (const float*)d_in[0];
    const float* w1    = (const float*)d_in[1];
    const float* b1    = (const float*)d_in[2];
    const float* bn1_g = (const float*)d_in[3];
    const float* bn1_b = (const float*)d_in[4];
    const float* bn1_m = (const float*)d_in[5];
    const float* bn1_v = (const float*)d_in[6];
    const float* caw1  = (const float*)d_in[7];
    const float* cab1  = (const float*)d_in[8];
    const float* caw2  = (const float*)d_in[9];
    const float* cab2  = (const float*)d_in[10];
    const float* w2    = (const float*)d_in[11];
    const float* b2    = (const float*)d_in[12];
    const float* bn2_g = (const float*)d_in[13];
    const float* bn2_b = (const float*)d_in[14];
    const float* bn2_m = (const float*)d_in[15];
    const float* bn2_v = (const float*)d_in[16];
    const float* w3    = (const float*)d_in[17];
    const float* b3    = (const float*)d_in[18];

    float* ws    = (float*)d_ws;
    float* gT    = ws;                  // [768][64]
    float* h1T   = ws + 49152;          // [1536][64]
    float* r_pre = ws + 147456;         // [96][64]
    float* h2T   = ws + 153600;         // [768][64]
    float* h1gT  = ws + 202752;         // [1536][64]
    float* out = (float*)d_out;

    pool_kernel<<<(B_ * C_) / 4, 256, 0, stream>>>(x, gT, r_pre);
    l1r_kernel<<<C2_ / 6, 512, 0, stream>>>(
        gT, w1, b1, bn1_g, bn1_b, bn1_m, bn1_v, caw1, h1T, r_pre);
    gate_kernel<<<C2_ / 8, 512, 0, stream>>>(
        r_pre, cab1, caw2, cab2, h1T, h1gT);
    l4_kernel<<<C_ / 2, 512, 0, stream>>>(
        h1gT, w2, b2, bn2_g, bn2_b, bn2_m, bn2_v, h2T);
    l5_kernel<<<B_, 256, 0, stream>>>(h2T, w3, b3, out);
}

// Round 10
// 66.972 us; speedup vs baseline: 2.4749x; 2.4749x over previous
//
#include <hip/hip_runtime.h>
#include <hip/hip_bf16.h>
#include <math.h>

#define B_   64
#define C_   768
#define C2_  1536
#define R_   96
#define E_   16
#define HW_  1024

typedef float f32x4 __attribute__((ext_vector_type(4)));

__device__ __forceinline__ float gelu_exact(float x) {
    return 0.5f * x * (1.0f + erff(x * 0.70710678118654752440f));
}

// -------- Kernel 1: global average pool [B,C,H,W] -> gT[C][B] ---------------
// one wave per row of 1024 contiguous floats; nontemporal (no reuse).
__global__ __launch_bounds__(256) void pool_kernel(const float* __restrict__ x,
                                                   float* __restrict__ gT) {
    const int wave = threadIdx.x >> 6;
    const int lane = threadIdx.x & 63;
    const int row  = blockIdx.x * 4 + wave;
    const int b = row / C_;
    const int c = row % C_;
    const f32x4* p = reinterpret_cast<const f32x4*>(x + (size_t)row * HW_);
    f32x4 a0 = __builtin_nontemporal_load(p + lane +   0);
    f32x4 a1 = __builtin_nontemporal_load(p + lane +  64);
    f32x4 a2 = __builtin_nontemporal_load(p + lane + 128);
    f32x4 a3 = __builtin_nontemporal_load(p + lane + 192);
    float s = (a0.x + a0.y + a0.z + a0.w) + (a1.x + a1.y + a1.z + a1.w)
            + (a2.x + a2.y + a2.z + a2.w) + (a3.x + a3.y + a3.z + a3.w);
    #pragma unroll
    for (int off = 32; off >= 1; off >>= 1) s += __shfl_xor(s, off);
    if (lane == 0) gT[c * B_ + b] = s * (1.0f / (float)HW_);
}

// -------- Generic fused GEMV layer: outT = gelu([BN](inT^T @ W.T + bias)) ---
// 512 threads = 8 waves; block computes 2 out-channels x 64 b, split-K.
template<int K, bool BN>
__global__ __launch_bounds__(512) void gemv2_kernel(
    const float* __restrict__ inT,   // [K][64]
    const float* __restrict__ W,     // [Cout][K]
    const float* __restrict__ bias,
    const float* __restrict__ bn_g, const float* __restrict__ bn_b,
    const float* __restrict__ bn_m, const float* __restrict__ bn_v,
    float* __restrict__ outT)        // [Cout][64]
{
    __shared__ __align__(16) float wl[2 * K];
    __shared__ float part[2][8][64];
    const int t  = threadIdx.x;
    const int c0 = blockIdx.x * 2;
    {   // stage 2 weight rows (2K floats = K/2 float4)
        const float4* src = reinterpret_cast<const float4*>(W + (size_t)c0 * K);
        float4* dst = reinterpret_cast<float4*>(wl);
        #pragma unroll
        for (int i = t; i < K / 2; i += 512) dst[i] = src[i];
    }
    __syncthreads();
    const int b = t & 63, w = t >> 6;          // wave id = K-chunk
    const int kc = w * (K / 8);
    const float* w0 = wl + kc;
    const float* w1 = wl + K + kc;
    const float* g  = inT + (size_t)kc * B_ + b;
    float a0 = 0.f, a1 = 0.f;
    #pragma unroll 16
    for (int k = 0; k < K / 8; ++k) {
        float gv = g[k * B_];                  // coalesced across lanes
        a0 = fmaf(gv, w0[k], a0);              // LDS broadcast reads
        a1 = fmaf(gv, w1[k], a1);
    }
    part[0][w][b] = a0;
    part[1][w][b] = a1;
    __syncthreads();
    if (t < 128) {
        const int ci = t >> 6, bb = t & 63, c = c0 + ci;
        float s = (part[ci][0][bb] + part[ci][1][bb])
                + (part[ci][2][bb] + part[ci][3][bb])
                + (part[ci][4][bb] + part[ci][5][bb])
                + (part[ci][6][bb] + part[ci][7][bb]);
        s += bias[c];
        if (BN) s = (s - bn_m[c]) * rsqrtf(bn_v[c] + 1e-5f) * bn_g[c] + bn_b[c];
        outT[(size_t)c * B_ + bb] = gelu_exact(s);
    }
}

// -------- L2: rT = gelu(h1 @ caw1.T + cab1); 96 blocks, 1 c each ------------
__global__ __launch_bounds__(512) void l2_kernel(
    const float* __restrict__ h1T, const float* __restrict__ caw1,
    const float* __restrict__ cab1, float* __restrict__ rT)
{
    __shared__ __align__(16) float wl[C2_];
    __shared__ float part[8][64];
    const int t = threadIdx.x;
    const int c = blockIdx.x;
    {
        const float4* src = reinterpret_cast<const float4*>(caw1 + (size_t)c * C2_);
        float4* dst = reinterpret_cast<float4*>(wl);
        if (t < 384) dst[t] = src[t];
    }
    __syncthreads();
    const int b = t & 63, w = t >> 6;
    const int kc = w * 192;
    const float* hp = h1T + (size_t)kc * B_ + b;
    float a0 = 0.f, a1 = 0.f, a2 = 0.f;
    #pragma unroll 8
    for (int k = 0; k < 64; ++k) {
        a0 = fmaf(hp[k * B_],         wl[kc + k],       a0);
        a1 = fmaf(hp[(k + 64) * B_],  wl[kc + k + 64],  a1);
        a2 = fmaf(hp[(k + 128) * B_], wl[kc + k + 128], a2);
    }
    part[w][b] = (a0 + a1) + a2;
    __syncthreads();
    if (t < 64) {
        float s = 0.f;
        #pragma unroll
        for (int ww = 0; ww < 8; ++ww) s += part[ww][t];
        rT[(size_t)c * B_ + t] = gelu_exact(s + cab1[c]);
    }
}

// -------- Gate: h1gT = h1T * sigmoid(2*(r @ caw2.T + cab2)); wave = 1 c -----
// no LDS, no syncs; caw2 row is wave-uniform (scalarized loads).
__global__ __launch_bounds__(512) void gate_kernel(
    const float* __restrict__ rT, const float* __restrict__ caw2,
    const float* __restrict__ cab2,
    const float* __restrict__ h1T, float* __restrict__ h1gT)
{
    const int t = threadIdx.x;
    const int b = t & 63, w = t >> 6;
    const int c = __builtin_amdgcn_readfirstlane(blockIdx.x * 8 + w);
    const float* wr = caw2 + (size_t)c * R_;   // wave-uniform row
    const float* rp = rT + b;
    float a0 = 0.f, a1 = 0.f;
    #pragma unroll 8
    for (int k = 0; k < 48; ++k) {
        a0 = fmaf(rp[k * B_],        wr[k],      a0);
        a1 = fmaf(rp[(k + 48) * B_], wr[k + 48], a1);
    }
    float a = a0 + a1 + cab2[c];
    float sig = 1.0f / (1.0f + expf(-2.0f * a));
    h1gT[(size_t)c * B_ + b] = h1T[(size_t)c * B_ + b] * sig;
}

// -------- L5: scores + top-2 + softmax; one block per b; no w3 staging ------
__global__ __launch_bounds__(256) void l5_kernel(
    const float* __restrict__ h2T, const float* __restrict__ w3,
    const float* __restrict__ b3, float* __restrict__ out)
{
    __shared__ float part[256];
    __shared__ float sc[E_];
    const int t = threadIdx.x;
    const int b = blockIdx.x;
    const int e = t & 15, kg = t >> 4;            // kg in [0,16)
    const float* wr = w3 + (size_t)e * C_ + kg * 48;   // L2-hot after block 0
    const float* hv = h2T + (size_t)kg * 48 * B_ + b;  // broadcast across e
    float acc = 0.f;
    #pragma unroll 8
    for (int j = 0; j < 48; ++j) acc = fmaf(hv[j * B_], wr[j], acc);
    part[t] = acc;
    __syncthreads();
    if (t < E_) {
        float s = b3[t];
        #pragma unroll
        for (int kgi = 0; kgi < 16; ++kgi) s += part[kgi * 16 + t];
        sc[t] = s;
    }
    __syncthreads();
    if (t == 0) {
        int i0 = 0; float v0 = sc[0];
        #pragma unroll
        for (int i = 1; i < E_; ++i) { if (sc[i] > v0) { v0 = sc[i]; i0 = i; } }
        int i1 = -1; float v1 = -INFINITY;
        #pragma unroll
        for (int i = 0; i < E_; ++i) {
            if (i == i0) continue;
            if (sc[i] > v1) { v1 = sc[i]; i1 = i; }
        }
        float e1 = expf((v1 - v0) * 0.5f);
        float inv = 1.0f / (1.0f + e1);
        out[b * 2 + 0] = (float)i0;
        out[b * 2 + 1] = (float)i1;
        out[2 * B_ + b * 2 + 0] = inv;
        out[2 * B_ + b * 2 + 1] = e1 * inv;
    }
}

extern "C" void kernel_launch(void* const* d_in, const int* in_sizes, int n_in,
                              void* d_out, int out_size, void* d_ws, size_t ws_size,
                              hipStream_t stream) {
    const float* x     = (const float*)d_in[0];
    const float* w1    = (const float*)d_in[1];
    const float* b1    = (const float*)d_in[2];
    const float* bn1_g = (const float*)d_in[3];
    const float* bn1_b = (const float*)d_in[4];
    const float* bn1_m = (const float*)d_in[5];
    const float* bn1_v = (const float*)d_in[6];
    const float* caw1  = (const float*)d_in[7];
    const float* cab1  = (const float*)d_in[8];
    const float* caw2  = (const float*)d_in[9];
    const float* cab2  = (const float*)d_in[10];
    const float* w2    = (const float*)d_in[11];
    const float* b2    = (const float*)d_in[12];
    const float* bn2_g = (const float*)d_in[13];
    const float* bn2_b = (const float*)d_in[14];
    const float* bn2_m = (const float*)d_in[15];
    const float* bn2_v = (const float*)d_in[16];
    const float* w3    = (const float*)d_in[17];
    const float* b3    = (const float*)d_in[18];

    float* ws   = (float*)d_ws;
    float* gT   = ws;                  // [768][64]
    float* h1T  = ws + 49152;          // [1536][64]
    float* rT   = ws + 147456;         // [96][64]
    float* h2T  = ws + 153600;         // [768][64]
    float* h1gT = ws + 202752;         // [1536][64]
    float* out = (float*)d_out;

    pool_kernel<<<(B_ * C_) / 4, 256, 0, stream>>>(x, gT);
    gemv2_kernel<C_, true><<<C2_ / 2, 512, 0, stream>>>(
        gT, w1, b1, bn1_g, bn1_b, bn1_m, bn1_v, h1T);
    l2_kernel<<<R_, 512, 0, stream>>>(h1T, caw1, cab1, rT);
    gate_kernel<<<C2_ / 8, 512, 0, stream>>>(rT, caw2, cab2, h1T, h1gT);
    gemv2_kernel<C2_, true><<<C_ / 2, 512, 0, stream>>>(
        h1gT, w2, b2, bn2_g, bn2_b, bn2_m, bn2_v, h2T);
    l5_kernel<<<B_, 256, 0, stream>>>(h2T, w3, b3, out);
}

// Round 11
// 66.262 us; speedup vs baseline: 2.5014x; 1.0107x over previous
//
#include <hip/hip_runtime.h>
#include <hip/hip_bf16.h>
#include <math.h>

#define B_   64
#define C_   768
#define C2_  1536
#define R_   96
#define E_   16
#define HW_  1024

typedef float f32x4 __attribute__((ext_vector_type(4)));

__device__ __forceinline__ float gelu_exact(float x) {
    return 0.5f * x * (1.0f + erff(x * 0.70710678118654752440f));
}

__device__ __forceinline__ f32x4 nt_load4(const float* p) {
    return __builtin_nontemporal_load(reinterpret_cast<const f32x4*>(p));
}

// -------- Kernel 1: global average pool [B,C,H,W] -> gT[C][B] ---------------
__global__ __launch_bounds__(256) void pool_kernel(const float* __restrict__ x,
                                                   float* __restrict__ gT) {
    const int wave = threadIdx.x >> 6;
    const int lane = threadIdx.x & 63;
    const int row  = blockIdx.x * 4 + wave;
    const int b = row / C_;
    const int c = row % C_;
    const float* p = x + (size_t)row * HW_;
    f32x4 a0 = nt_load4(p + lane * 4 +    0);
    f32x4 a1 = nt_load4(p + lane * 4 +  256);
    f32x4 a2 = nt_load4(p + lane * 4 +  512);
    f32x4 a3 = nt_load4(p + lane * 4 +  768);
    float s = (a0.x + a0.y + a0.z + a0.w) + (a1.x + a1.y + a1.z + a1.w)
            + (a2.x + a2.y + a2.z + a2.w) + (a3.x + a3.y + a3.z + a3.w);
    #pragma unroll
    for (int off = 32; off >= 1; off >>= 1) s += __shfl_xor(s, off);
    if (lane == 0) gT[c * B_ + b] = s * (1.0f / (float)HW_);
}

// -------- Generic fused GEMV layer: 4 out-channels per block ----------------
// 512 threads = 8 waves; wave w owns K-chunk w; each thread accumulates all
// 4 channels (input loaded once, 4 fmaf -> ILP 4). LDS tree-reduce at end.
// Weight staging is nontemporal (read once chip-wide); activations stay L2-hot.
template<int K, bool BN>
__global__ __launch_bounds__(512) void gemv4_kernel(
    const float* __restrict__ inT,   // [K][64]
    const float* __restrict__ W,     // [Cout][K]
    const float* __restrict__ bias,
    const float* __restrict__ bn_g, const float* __restrict__ bn_b,
    const float* __restrict__ bn_m, const float* __restrict__ bn_v,
    float* __restrict__ outT)        // [Cout][64]
{
    __shared__ __align__(16) float wl[4 * K];
    __shared__ float part[4][8][64];
    const int t  = threadIdx.x;
    const int c0 = blockIdx.x * 4;
    {   // stage 4 weight rows (4K floats = K float4)
        const float* src = W + (size_t)c0 * K;
        f32x4* dst = reinterpret_cast<f32x4*>(wl);
        #pragma unroll
        for (int i = t; i < K; i += 512) dst[i] = nt_load4(src + i * 4);
    }
    __syncthreads();
    const int b = t & 63, w = t >> 6;          // wave id = K-chunk
    const int kc = w * (K / 8);
    const float* w0 = wl + kc;
    const float* g  = inT + (size_t)kc * B_ + b;
    float a0 = 0.f, a1 = 0.f, a2 = 0.f, a3 = 0.f;
    #pragma unroll 8
    for (int k = 0; k < K / 8; ++k) {
        float gv = g[k * B_];                  // coalesced across lanes
        a0 = fmaf(gv, w0[k],         a0);      // LDS broadcast reads
        a1 = fmaf(gv, w0[K + k],     a1);
        a2 = fmaf(gv, w0[2 * K + k], a2);
        a3 = fmaf(gv, w0[3 * K + k], a3);
    }
    part[0][w][b] = a0;
    part[1][w][b] = a1;
    part[2][w][b] = a2;
    part[3][w][b] = a3;
    __syncthreads();
    if (t < 256) {
        const int ci = t >> 6, bb = t & 63, c = c0 + ci;
        float s = (part[ci][0][bb] + part[ci][1][bb])
                + (part[ci][2][bb] + part[ci][3][bb])
                + (part[ci][4][bb] + part[ci][5][bb])
                + (part[ci][6][bb] + part[ci][7][bb]);
        s += bias[c];
        if (BN) s = (s - bn_m[c]) * rsqrtf(bn_v[c] + 1e-5f) * bn_g[c] + bn_b[c];
        outT[(size_t)c * B_ + bb] = gelu_exact(s);
    }
}

// -------- L2: rT = gelu(h1 @ caw1.T + cab1); 96 blocks, 1 c each ------------
__global__ __launch_bounds__(512) void l2_kernel(
    const float* __restrict__ h1T, const float* __restrict__ caw1,
    const float* __restrict__ cab1, float* __restrict__ rT)
{
    __shared__ __align__(16) float wl[C2_];
    __shared__ float part[8][64];
    const int t = threadIdx.x;
    const int c = blockIdx.x;
    {
        const float* src = caw1 + (size_t)c * C2_;
        f32x4* dst = reinterpret_cast<f32x4*>(wl);
        if (t < 384) dst[t] = nt_load4(src + t * 4);
    }
    __syncthreads();
    const int b = t & 63, w = t >> 6;
    const int kc = w * 192;
    const float* hp = h1T + (size_t)kc * B_ + b;
    float a0 = 0.f, a1 = 0.f, a2 = 0.f;
    #pragma unroll 8
    for (int k = 0; k < 64; ++k) {
        a0 = fmaf(hp[k * B_],         wl[kc + k],       a0);
        a1 = fmaf(hp[(k + 64) * B_],  wl[kc + k + 64],  a1);
        a2 = fmaf(hp[(k + 128) * B_], wl[kc + k + 128], a2);
    }
    part[w][b] = (a0 + a1) + a2;
    __syncthreads();
    if (t < 64) {
        float s = 0.f;
        #pragma unroll
        for (int ww = 0; ww < 8; ++ww) s += part[ww][t];
        rT[(size_t)c * B_ + t] = gelu_exact(s + cab1[c]);
    }
}

// -------- Gate: h1gT = h1T * sigmoid(2*(r @ caw2.T + cab2)); wave = 1 c -----
__global__ __launch_bounds__(512) void gate_kernel(
    const float* __restrict__ rT, const float* __restrict__ caw2,
    const float* __restrict__ cab2,
    const float* __restrict__ h1T, float* __restrict__ h1gT)
{
    const int t = threadIdx.x;
    const int b = t & 63, w = t >> 6;
    const int c = __builtin_amdgcn_readfirstlane(blockIdx.x * 8 + w);
    const float* wr = caw2 + (size_t)c * R_;   // wave-uniform row
    const float* rp = rT + b;
    float a0 = 0.f, a1 = 0.f;
    #pragma unroll 8
    for (int k = 0; k < 48; ++k) {
        a0 = fmaf(rp[k * B_],        wr[k],      a0);
        a1 = fmaf(rp[(k + 48) * B_], wr[k + 48], a1);
    }
    float a = a0 + a1 + cab2[c];
    float sig = 1.0f / (1.0f + expf(-2.0f * a));
    h1gT[(size_t)c * B_ + b] = h1T[(size_t)c * B_ + b] * sig;
}

// -------- L5: scores + top-2 + softmax; one block per b; no w3 staging ------
__global__ __launch_bounds__(256) void l5_kernel(
    const float* __restrict__ h2T, const float* __restrict__ w3,
    const float* __restrict__ b3, float* __restrict__ out)
{
    __shared__ float part[256];
    __shared__ float sc[E_];
    const int t = threadIdx.x;
    const int b = blockIdx.x;
    const int e = t & 15, kg = t >> 4;            // kg in [0,16)
    const float* wr = w3 + (size_t)e * C_ + kg * 48;   // L2-hot after block 0
    const float* hv = h2T + (size_t)kg * 48 * B_ + b;  // broadcast across e
    float acc = 0.f;
    #pragma unroll 8
    for (int j = 0; j < 48; ++j) acc = fmaf(hv[j * B_], wr[j], acc);
    part[t] = acc;
    __syncthreads();
    if (t < E_) {
        float s = b3[t];
        #pragma unroll
        for (int kgi = 0; kgi < 16; ++kgi) s += part[kgi * 16 + t];
        sc[t] = s;
    }
    __syncthreads();
    if (t == 0) {
        int i0 = 0; float v0 = sc[0];
        #pragma unroll
        for (int i = 1; i < E_; ++i) { if (sc[i] > v0) { v0 = sc[i]; i0 = i; } }
        int i1 = -1; float v1 = -INFINITY;
        #pragma unroll
        for (int i = 0; i < E_; ++i) {
            if (i == i0) continue;
            if (sc[i] > v1) { v1 = sc[i]; i1 = i; }
        }
        float e1 = expf((v1 - v0) * 0.5f);
        float inv = 1.0f / (1.0f + e1);
        out[b * 2 + 0] = (float)i0;
        out[b * 2 + 1] = (float)i1;
        out[2 * B_ + b * 2 + 0] = inv;
        out[2 * B_ + b * 2 + 1] = e1 * inv;
    }
}

extern "C" void kernel_launch(void* const* d_in, const int* in_sizes, int n_in,
                              void* d_out, int out_size, void* d_ws, size_t ws_size,
                              hipStream_t stream) {
    const float* x     = (const float*)d_in[0];
    const float* w1    = (const float*)d_in[1];
    const float* b1    = (const float*)d_in[2];
    const float* bn1_g = (const float*)d_in[3];
    const float* bn1_b = (const float*)d_in[4];
    const float* bn1_m = (const float*)d_in[5];
    const float* bn1_v = (const float*)d_in[6];
    const float* caw1  = (const float*)d_in[7];
    const float* cab1  = (const float*)d_in[8];
    const float* caw2  = (const float*)d_in[9];
    const float* cab2  = (const float*)d_in[10];
    const float* w2    = (const float*)d_in[11];
    const float* b2    = (const float*)d_in[12];
    const float* bn2_g = (const float*)d_in[13];
    const float* bn2_b = (const float*)d_in[14];
    const float* bn2_m = (const float*)d_in[15];
    const float* bn2_v = (const float*)d_in[16];
    const float* w3    = (const float*)d_in[17];
    const float* b3    = (const float*)d_in[18];

    float* ws   = (float*)d_ws;
    float* gT   = ws;                  // [768][64]
    float* h1T  = ws + 49152;          // [1536][64]
    float* rT   = ws + 147456;         // [96][64]
    float* h2T  = ws + 153600;         // [768][64]
    float* h1gT = ws + 202752;         // [1536][64]
    float* out = (float*)d_out;

    pool_kernel<<<(B_ * C_) / 4, 256, 0, stream>>>(x, gT);
    gemv4_kernel<C_, true><<<C2_ / 4, 512, 0, stream>>>(
        gT, w1, b1, bn1_g, bn1_b, bn1_m, bn1_v, h1T);
    l2_kernel<<<R_, 512, 0, stream>>>(h1T, caw1, cab1, rT);
    gate_kernel<<<C2_ / 8, 512, 0, stream>>>(rT, caw2, cab2, h1T, h1gT);
    gemv4_kernel<C2_, true><<<C_ / 4, 512, 0, stream>>>(
        h1gT, w2, b2, bn2_g, bn2_b, bn2_m, bn2_v, h2T);
    l5_kernel<<<B_, 256, 0, stream>>>(h2T, w3, b3, out);
}